// Round 4
// baseline (548.147 us; speedup 1.0000x reference)
//
#include <hip/hip_runtime.h>
#include <hip/hip_bf16.h>

#define NN 50000
#define EE 800000

typedef __attribute__((ext_vector_type(8))) short short8;
typedef __attribute__((ext_vector_type(4))) short short4v;
typedef __attribute__((ext_vector_type(4))) float f32x4;

__device__ __forceinline__ float bf2f(ushort u) {
  union { unsigned u; float f; } v; v.u = ((unsigned)u) << 16; return v.f;
}
__device__ __forceinline__ ushort f2bf(float f) {
  union { float f; unsigned u; } v; v.f = f;
  unsigned r = v.u + 0x7FFFu + ((v.u >> 16) & 1u);  // RNE
  return (ushort)(r >> 16);
}
__device__ __forceinline__ float silu(float v) {
  return v * __builtin_amdgcn_rcpf(1.f + __expf(-v));
}

// ---- merged prep: h->bf16, weights->transposed bf16, agg zeroing ----
__global__ void prep_kernel(const float* __restrict__ h, ushort* __restrict__ hb,
                            const float* __restrict__ W1, const float* __restrict__ W2,
                            const float* __restrict__ W3,
                            ushort* __restrict__ W1t, ushort* __restrict__ W2t,
                            ushort* __restrict__ W3t, float* __restrict__ agg) {
  int b = blockIdx.x, tid = threadIdx.x;
  if (b < 3125) {                         // h -> hb, 8 elems/thread
    int i = b * 256 + tid;
    const float4* p = (const float4*)h;
    float4 a = p[2*i], c = p[2*i+1];
    short8 o;
    o[0]=f2bf(a.x); o[1]=f2bf(a.y); o[2]=f2bf(a.z); o[3]=f2bf(a.w);
    o[4]=f2bf(c.x); o[5]=f2bf(c.y); o[6]=f2bf(c.z); o[7]=f2bf(c.w);
    *(short8*)(hb + 8*i) = o;
  } else if (b < 3325) {                  // weights
    int i = (b - 3125) * 256 + tid;
    if (i < 32768) {                      // W1t [128 n][256 k]
      int n = i >> 8, k = i & 255;
      W1t[i] = f2bf(W1[k*128 + n]);
    } else if (i < 49152) {               // W2t [128 n][128 k]
      int j = i - 32768, n = j >> 7, k = j & 127;
      W2t[j] = f2bf(W2[k*128 + n]);
    } else if (i < 51200) {               // W3t [16 m][128 k], rows 9..15 zero
      int j = i - 49152, n = j >> 7, k = j & 127;
      W3t[j] = (n < 9) ? f2bf(W3[k*9 + n]) : (ushort)0;
    }
  } else {                                // zero agg
    int i = (b - 3325) * 256 + tid;
    if (i < NN*9) agg[i] = 0.f;
  }
}

// Wave-autonomous edge kernel: each wave owns 32 edges, no __syncthreads.
// Per wave: M=128 features (mf 0..7), N=32 edges (nf 0..1, col=l15).
// x-tile LDS layout: [16 oct][32 e][8 bf16] (oct = feature>>3) -> <=2-way banks.
template<bool USE_HB>
__global__ __launch_bounds__(256, 3)
void edge_kernel(const float* __restrict__ h, const ushort* __restrict__ hb,
                 const ushort* __restrict__ W1t, const ushort* __restrict__ W2t,
                 const ushort* __restrict__ W3t,
                 const float* __restrict__ W1,
                 const float* __restrict__ b1, const float* __restrict__ g1, const float* __restrict__ be1,
                 const float* __restrict__ b2, const float* __restrict__ g2, const float* __restrict__ be2,
                 const float* __restrict__ edge_attr, const float* __restrict__ edge_mask,
                 const float* __restrict__ coord_diff,
                 const int* __restrict__ row, const int* __restrict__ col,
                 float* __restrict__ agg) {
  // per-wave LDS: xbuf 8192 B + cdbuf 1280 B + phibuf 2560 B = 12032 B
  __shared__ __align__(16) char smem[4 * 12032];
  const int tid  = threadIdx.x;
  const int lane = tid & 63;
  const int w    = tid >> 6;
  const int l15  = lane & 15;
  const int lh   = lane >> 4;

  char*  wb     = smem + w * 12032;
  ushort* xbuf  = (ushort*)wb;
  float*  cdbuf = (float*)(wb + 8192);
  float*  phibuf= (float*)(wb + 9472);

  const int we0 = (blockIdx.x * 4 + w) * 32;       // wave's first edge

  // ---- P0: per-edge scalars + cd staging (wave-local) ----
  int rn[2], cn[2]; float ea[2], em[2];
  #pragma unroll
  for (int nf = 0; nf < 2; ++nf) {
    int e = we0 + nf*16 + l15;
    rn[nf] = row[e]; cn[nf] = col[e];
    ea[nf] = edge_attr[e]; em[nf] = edge_mask[e];
  }
  {
    const float* cdsrc = coord_diff + (size_t)we0 * 9;   // 288 floats
    *(float4*)(cdbuf + lane*4) = *(const float4*)(cdsrc + lane*4);
    if (lane < 8)
      *(float4*)(cdbuf + 256 + lane*4) = *(const float4*)(cdsrc + 256 + lane*4);
  }

  // ---- GEMM1: out1T[n][e], K=256; B-frags straight from hb (no staging) ----
  f32x4 acc[8][2] = {};
  #pragma unroll
  for (int k0 = 0; k0 < 8; ++k0) {
    short8 b[2];
    #pragma unroll
    for (int nf = 0; nf < 2; ++nf) {
      int node = (k0 < 4) ? rn[nf] : cn[nf];
      int koff = (k0 & 3)*32 + lh*8;
      if (USE_HB) {
        b[nf] = *(const short8*)(hb + (size_t)node*128 + koff);
      } else {
        const float* s = h + (size_t)node*128 + koff;
        float4 u = *(const float4*)s, vq = *(const float4*)(s + 4);
        short8 t;
        t[0]=f2bf(u.x); t[1]=f2bf(u.y); t[2]=f2bf(u.z); t[3]=f2bf(u.w);
        t[4]=f2bf(vq.x); t[5]=f2bf(vq.y); t[6]=f2bf(vq.z); t[7]=f2bf(vq.w);
        b[nf] = t;
      }
    }
    #pragma unroll
    for (int mf = 0; mf < 8; ++mf) {
      short8 a = *(const short8*)(W1t + (size_t)(mf*16 + l15)*256 + k0*32 + lh*8);
      acc[mf][0] = __builtin_amdgcn_mfma_f32_16x16x32_bf16(a, b[0], acc[mf][0], 0, 0, 0);
      acc[mf][1] = __builtin_amdgcn_mfma_f32_16x16x32_bf16(a, b[1], acc[mf][1], 0, 0, 0);
    }
  }

  // ---- epi1 (bias + edge_attr column) + LN1 stats, in registers ----
  float s[2] = {0.f,0.f}, q[2] = {0.f,0.f};
  {
    const float* wl = W1 + 256*128;
    #pragma unroll
    for (int mf = 0; mf < 8; ++mf) {
      float4 bq = *(const float4*)(b1 + mf*16 + lh*4);
      float4 wq = *(const float4*)(wl + mf*16 + lh*4);
      #pragma unroll
      for (int nf = 0; nf < 2; ++nf)
        #pragma unroll
        for (int j = 0; j < 4; ++j) {
          float t = acc[mf][nf][j] + ((const float*)&bq)[j] + ea[nf] * ((const float*)&wq)[j];
          acc[mf][nf][j] = t; s[nf] += t; q[nf] += t*t;
        }
    }
  }
  #pragma unroll
  for (int nf = 0; nf < 2; ++nf) {
    s[nf] += __shfl_xor(s[nf], 16, 64); s[nf] += __shfl_xor(s[nf], 32, 64);
    q[nf] += __shfl_xor(q[nf], 16, 64); q[nf] += __shfl_xor(q[nf], 32, 64);
  }
  // ---- LN1 apply + SiLU -> xbuf ----
  {
    float m[2], rs[2];
    #pragma unroll
    for (int nf = 0; nf < 2; ++nf) {
      m[nf]  = s[nf] * (1.f/128.f);
      rs[nf] = rsqrtf(q[nf] * (1.f/128.f) - m[nf]*m[nf] + 1e-5f);
    }
    #pragma unroll
    for (int mf = 0; mf < 8; ++mf) {
      float4 gq  = *(const float4*)(g1 + mf*16 + lh*4);
      float4 beq = *(const float4*)(be1 + mf*16 + lh*4);
      #pragma unroll
      for (int nf = 0; nf < 2; ++nf) {
        int e32 = nf*16 + l15;
        short4v o;
        #pragma unroll
        for (int j = 0; j < 4; ++j) {
          float val = (acc[mf][nf][j] - m[nf]) * rs[nf] * ((const float*)&gq)[j] + ((const float*)&beq)[j];
          o[j] = f2bf(silu(val));
        }
        *(short4v*)((char*)xbuf + ((mf*2 + (lh>>1))*32 + e32)*16 + (lh&1)*8) = o;
      }
    }
  }

  // ---- GEMM2: K=128, x1 from xbuf (wave-local; lgkmcnt ordering only) ----
  f32x4 acc2[8][2] = {};
  #pragma unroll
  for (int k0 = 0; k0 < 4; ++k0) {
    short8 b[2];
    #pragma unroll
    for (int nf = 0; nf < 2; ++nf) {
      int e32 = nf*16 + l15;
      b[nf] = *(const short8*)((char*)xbuf + ((k0*4 + lh)*32 + e32)*16);
    }
    #pragma unroll
    for (int mf = 0; mf < 8; ++mf) {
      short8 a = *(const short8*)(W2t + (size_t)(mf*16 + l15)*128 + k0*32 + lh*8);
      acc2[mf][0] = __builtin_amdgcn_mfma_f32_16x16x32_bf16(a, b[0], acc2[mf][0], 0, 0, 0);
      acc2[mf][1] = __builtin_amdgcn_mfma_f32_16x16x32_bf16(a, b[1], acc2[mf][1], 0, 0, 0);
    }
  }

  // ---- epi2 + LN2 ----
  float s2[2] = {0.f,0.f}, q2[2] = {0.f,0.f};
  #pragma unroll
  for (int mf = 0; mf < 8; ++mf) {
    float4 bq = *(const float4*)(b2 + mf*16 + lh*4);
    #pragma unroll
    for (int nf = 0; nf < 2; ++nf)
      #pragma unroll
      for (int j = 0; j < 4; ++j) {
        float t = acc2[mf][nf][j] + ((const float*)&bq)[j];
        acc2[mf][nf][j] = t; s2[nf] += t; q2[nf] += t*t;
      }
  }
  #pragma unroll
  for (int nf = 0; nf < 2; ++nf) {
    s2[nf] += __shfl_xor(s2[nf], 16, 64); s2[nf] += __shfl_xor(s2[nf], 32, 64);
    q2[nf] += __shfl_xor(q2[nf], 16, 64); q2[nf] += __shfl_xor(q2[nf], 32, 64);
  }
  {
    float m[2], rs[2];
    #pragma unroll
    for (int nf = 0; nf < 2; ++nf) {
      m[nf]  = s2[nf] * (1.f/128.f);
      rs[nf] = rsqrtf(q2[nf] * (1.f/128.f) - m[nf]*m[nf] + 1e-5f);
    }
    #pragma unroll
    for (int mf = 0; mf < 8; ++mf) {
      float4 gq  = *(const float4*)(g2 + mf*16 + lh*4);
      float4 beq = *(const float4*)(be2 + mf*16 + lh*4);
      #pragma unroll
      for (int nf = 0; nf < 2; ++nf) {
        int e32 = nf*16 + l15;
        short4v o;
        #pragma unroll
        for (int j = 0; j < 4; ++j) {
          float val = (acc2[mf][nf][j] - m[nf]) * rs[nf] * ((const float*)&gq)[j] + ((const float*)&beq)[j];
          o[j] = f2bf(silu(val));
        }
        *(short4v*)((char*)xbuf + ((mf*2 + (lh>>1))*32 + e32)*16 + (lh&1)*8) = o;
      }
    }
  }

  // ---- GEMM3: phiT[m3][e], M=16, K=128 ----
  {
    f32x4 acc3[2] = {};
    #pragma unroll
    for (int k0 = 0; k0 < 4; ++k0) {
      short8 a = *(const short8*)(W3t + (size_t)l15*128 + k0*32 + lh*8);
      #pragma unroll
      for (int nf = 0; nf < 2; ++nf) {
        int e32 = nf*16 + l15;
        short8 b = *(const short8*)((char*)xbuf + ((k0*4 + lh)*32 + e32)*16);
        acc3[nf] = __builtin_amdgcn_mfma_f32_16x16x32_bf16(a, b, acc3[nf], 0, 0, 0);
      }
    }
    #pragma unroll
    for (int nf = 0; nf < 2; ++nf) {
      int e32 = nf*16 + l15;
      *(f32x4*)(phibuf + e32*20 + lh*4) = acc3[nf];   // phi[e][m3], stride 20
    }
  }

  // ---- final: trans[l][k] = sum_j cd[j][k]*phi[j*3+l]; scatter to agg ----
  if (lh < 3) {
    #pragma unroll
    for (int nf = 0; nf < 2; ++nf) {
      int e32 = nf*16 + l15;
      const float* cdp = cdbuf + e32*9;
      const float* php = phibuf + e32*20;
      int re = rn[nf]; float emv = em[nf];
      int l = lh;
      #pragma unroll
      for (int k = 0; k < 3; ++k) {
        float t = cdp[k]*php[l] + cdp[3+k]*php[3+l] + cdp[6+k]*php[6+l];
        unsafeAtomicAdd(&agg[(size_t)re*9 + l*3 + k], t * emv);
      }
    }
  }
}

__global__ void finalize_kernel(const float* __restrict__ coord, const float* __restrict__ node_mask,
                                const float* __restrict__ agg, float* __restrict__ out) {
  int i = blockIdx.x * 256 + threadIdx.x;
  if (i < NN*9) {
    int n = i / 9;
    out[i] = (coord[i] + agg[i] * 0.01f) * node_mask[n];
  }
}

extern "C" void kernel_launch(void* const* d_in, const int* in_sizes, int n_in,
                              void* d_out, int out_size, void* d_ws, size_t ws_size,
                              hipStream_t stream) {
  const float* h          = (const float*)d_in[0];
  const float* coord      = (const float*)d_in[1];
  const float* coord_diff = (const float*)d_in[2];
  const float* edge_attr  = (const float*)d_in[3];
  const float* edge_mask  = (const float*)d_in[4];
  const float* node_mask  = (const float*)d_in[5];
  const int*   rowi       = (const int*)d_in[6];
  const int*   coli       = (const int*)d_in[7];
  const float* W1  = (const float*)d_in[8];
  const float* b1  = (const float*)d_in[9];
  const float* g1  = (const float*)d_in[10];
  const float* be1 = (const float*)d_in[11];
  const float* W2  = (const float*)d_in[12];
  const float* b2  = (const float*)d_in[13];
  const float* g2  = (const float*)d_in[14];
  const float* be2 = (const float*)d_in[15];
  const float* W3  = (const float*)d_in[16];

  char* ws = (char*)d_ws;
  float*  agg = (float*)ws;                        // 1,800,000 B
  ushort* W1t = (ushort*)(ws + 1800064);           // 65,536 B
  ushort* W2t = (ushort*)(ws + 1865600);           // 32,768 B
  ushort* W3t = (ushort*)(ws + 1898368);           // 4,096 B
  ushort* hb  = (ushort*)(ws + 1902464);           // 12,800,000 B
  bool use_hb = ws_size >= (size_t)1902464 + 12800000;

  prep_kernel<<<3325 + (NN*9 + 255)/256, 256, 0, stream>>>(h, hb, W1, W2, W3, W1t, W2t, W3t, agg);
  if (use_hb) {
    edge_kernel<true><<<EE/128, 256, 0, stream>>>(h, hb, W1t, W2t, W3t, W1,
        b1, g1, be1, b2, g2, be2, edge_attr, edge_mask, coord_diff, rowi, coli, agg);
  } else {
    edge_kernel<false><<<EE/128, 256, 0, stream>>>(h, hb, W1t, W2t, W3t, W1,
        b1, g1, be1, b2, g2, be2, edge_attr, edge_mask, coord_diff, rowi, coli, agg);
  }
  finalize_kernel<<<(NN*9 + 255)/256, 256, 0, stream>>>(coord, node_mask, agg, (float*)d_out);
}